// Round 4
// baseline (71.867 us; speedup 1.0000x reference)
//
#include <hip/hip_runtime.h>
#include <hip/hip_bf16.h>

// Framing op: x [16, 1048576] f32 -> out [16, 2048, 2048] f32
// out[b, f, t] = (f*512 + t >= 1536) ? x[b, f*512 + t - 1536] : 0.0f
//
// SCATTER: input slice q (512 floats) lands in frames f=q+k (k=0..3) at
// position r + (3-k)*512. Virtual slices q=-3..-1 carry zeros (prefix).
// Every output element written exactly once -> no atomics, deterministic.
//
//  - no div/mod: b = blockIdx.y, slice group = blockIdx.x (8 slices/block)
//  - 4 slices per thread: 4 independent loads then 16 stores (4x load ILP)
//  - nontemporal loads+stores via clang ext_vector_type (HIP_vector_type
//    float4 is a struct and rejected by __builtin_nontemporal_*)
// Traffic: 64 MiB read + 256 MiB write = 335.5 MB -> ~52 us at 6.3 TB/s.

typedef float f4 __attribute__((ext_vector_type(4)));

#define T4_PER_B   262144u   // f4 per batch row of x
#define R4         128u      // f4 per 512-float slice
#define QI_COUNT   2051      // qi = 0..2050  (q = qi-3 = -3..2047)
#define NFRAMES    2048
#define F4_PER_FRAME 512u    // 2048 floats / 4

__global__ __launch_bounds__(256) void scatter_frames(
    const f4* __restrict__ x4, f4* __restrict__ out4)
{
    const unsigned tid  = threadIdx.x;
    const unsigned r4   = tid & (R4 - 1u);
    const unsigned sub  = tid >> 7;                  // 0..1
    const unsigned b    = blockIdx.y;
    const unsigned qi0  = blockIdx.x * 8u + sub;     // this thread: qi0 + 2*j

    const f4 zero = (f4){0.f, 0.f, 0.f, 0.f};
    const unsigned xbase = b * T4_PER_B + r4;        // fits 32-bit (max 2^22)
    const unsigned obase = b * (NFRAMES * F4_PER_FRAME) + r4; // max 2^24

    f4 v[4];
    int q[4];
#pragma unroll
    for (int j = 0; j < 4; ++j) {
        unsigned qi = qi0 + 2u * (unsigned)j;
        q[j] = (int)qi - 3;
        if (qi < (unsigned)QI_COUNT && q[j] >= 0) {
            v[j] = __builtin_nontemporal_load(&x4[xbase + (unsigned)q[j] * R4]);
        } else {
            v[j] = zero;
        }
    }

#pragma unroll
    for (int j = 0; j < 4; ++j) {
        unsigned qi = qi0 + 2u * (unsigned)j;
        if (qi >= (unsigned)QI_COUNT) continue;
#pragma unroll
        for (int k = 0; k < 4; ++k) {
            int f = q[j] + k;
            if (f >= 0 && f < NFRAMES) {
                __builtin_nontemporal_store(
                    v[j], &out4[obase + (unsigned)f * F4_PER_FRAME
                                + (unsigned)(3 - k) * R4]);
            }
        }
    }
}

extern "C" void kernel_launch(void* const* d_in, const int* in_sizes, int n_in,
                              void* d_out, int out_size, void* d_ws, size_t ws_size,
                              hipStream_t stream) {
    const f4* x4 = (const f4*)d_in[0];
    f4* out4 = (f4*)d_out;
    // 8 slices per block in x-dim: ceil(2051/8) = 257; batch in y-dim.
    dim3 block(256);
    dim3 grid(257, 16);
    scatter_frames<<<grid, block, 0, stream>>>(x4, out4);
}